// Round 7
// baseline (77.728 us; speedup 1.0000x reference)
//
#include <hip/hip_runtime.h>

// Spherical harmonics Y_l^m, l = 0..3, complex (re,im), packed [B,N,N,16,2] f32.
// Structure: 8 lanes per point (redundant closed-form compute, ~90 VALU ops),
// each lane stores exactly ONE float4 = quad (gt&7) of point (gt>>3), selected
// by a branchless 7-select float4 mux. No LDS, no barrier, no store bursts:
// out4[gt] is lane-consecutive -> every wave-store is 1 KiB contiguous.

constexpr int TPB = 256;

__device__ __forceinline__ float4 sel4(bool c, const float4& a, const float4& b) {
    // c ? a : b, componentwise (compiles to 4x v_cndmask)
    return make_float4(c ? a.x : b.x, c ? a.y : b.y, c ? a.z : b.z, c ? a.w : b.w);
}

__global__ __launch_bounds__(256) void spharm16_kernel(const float* __restrict__ X,
                                                       float4* __restrict__ out4,
                                                       int nf4) {
    const int gt = blockIdx.x * TPB + threadIdx.x;   // global float4 index
    if (gt >= nf4) return;                           // uniform except last wave
    const int p = gt >> 3;                           // point (8 lanes share)
    const int q = gt & 7;                            // quad within point

    const float x = X[3 * p + 0];
    const float y = X[3 * p + 1];
    const float z = X[3 * p + 2];

    // --- angles -----------------------------------------------------------
    const float r2   = x * x + y * y + z * z;
    const float rinv = rsqrtf(r2);
    const float ct   = z * rinv;                    // cos(theta)
    const float ct2  = ct * ct;
    const float st2  = fmaxf(1.0f - ct2, 0.0f);
    const float st   = sqrtf(st2);                  // sin(theta) >= 0

    const float rho2 = x * x + y * y;
    const float pinv = rsqrtf(rho2);
    const bool  okp  = rho2 > 0.0f;
    const float c1   = okp ? x * pinv : 1.0f;       // cos(phi)
    const float s1   = okp ? y * pinv : 0.0f;       // sin(phi)
    const float c2   = c1 * c1 - s1 * s1;           // cos(2phi)
    const float s2   = 2.0f * c1 * s1;               // sin(2phi)
    const float c3   = c2 * c1 - s2 * s1;           // cos(3phi)
    const float s3   = s2 * c1 + c2 * s1;           // sin(3phi)

    // --- normalized Legendre bases (Condon-Shortley folded into signs) ----
    const float S1  = 0.34549414947133547f * st;
    const float B10 = 0.48860251190291992f * ct;
    const float B20 = 0.63078313050504031f * (1.5f * ct2 - 0.5f);
    const float T21 = 0.77254840404637910f * ct * st;
    const float B22 = 0.38627420202318955f * st2;
    const float B30 = 0.74635266518023080f * ct * (2.5f * ct2 - 1.5f);
    const float B31 = 0.32318018411248776f * st * (1.0f - 5.0f * ct2);
    const float B32 = 1.02198547643188850f * ct * st2;
    const float T33 = 0.41722382363278404f * st2 * st;

    const float S1c1  = S1  * c1, S1s1  = S1  * s1;
    const float T21c1 = T21 * c1, T21s1 = T21 * s1;
    const float B22c2 = B22 * c2, B22s2 = B22 * s2;
    const float B31c1 = B31 * c1, B31s1 = B31 * s1;
    const float B32c2 = B32 * c2, B32s2 = B32 * s2;
    const float T33c3 = T33 * c3, T33s3 = T33 * s3;

    // --- the 8 quads of this point (pairs of (l,m) components) ------------
    const float4 q0 = make_float4(0.28209479177387814f, 0.0f,  S1c1, -S1s1); // (0,0),(1,-1)
    const float4 q1 = make_float4(B10,    0.0f,  -S1c1,  -S1s1);             // (1,0),(1,1)
    const float4 q2 = make_float4(B22c2, -B22s2,  T21c1, -T21s1);            // (2,-2),(2,-1)
    const float4 q3 = make_float4(B20,    0.0f,  -T21c1, -T21s1);            // (2,0),(2,1)
    const float4 q4 = make_float4(B22c2,  B22s2,  T33c3, -T33s3);            // (2,2),(3,-3)
    const float4 q5 = make_float4(B32c2, -B32s2, -B31c1,  B31s1);            // (3,-2),(3,-1)
    const float4 q6 = make_float4(B30,    0.0f,   B31c1,  B31s1);            // (3,0),(3,1)
    const float4 q7 = make_float4(B32c2,  B32s2, -T33c3, -T33s3);            // (3,2),(3,3)

    // --- branchless 8:1 float4 mux on q (28 v_cndmask) ---------------------
    const bool b0 = (q & 1) != 0;
    const bool b1 = (q & 2) != 0;
    const bool b2 = (q & 4) != 0;
    const float4 m01 = sel4(b0, q1, q0);
    const float4 m23 = sel4(b0, q3, q2);
    const float4 m45 = sel4(b0, q5, q4);
    const float4 m67 = sel4(b0, q7, q6);
    const float4 n0  = sel4(b1, m23, m01);
    const float4 n1  = sel4(b1, m67, m45);
    const float4 res = sel4(b2, n1, n0);

    out4[gt] = res;   // lane-consecutive: 1 KiB contiguous per wave-store
}

extern "C" void kernel_launch(void* const* d_in, const int* in_sizes, int n_in,
                              void* d_out, int out_size, void* d_ws, size_t ws_size,
                              hipStream_t stream) {
    const float* X = (const float*)d_in[0];
    float4* out4 = (float4*)d_out;
    const int npts = in_sizes[0] / 3;          // 524288
    const int nf4  = npts * 8;                 // one float4 per thread
    const int blocks = (nf4 + TPB - 1) / TPB;  // 16384
    spharm16_kernel<<<blocks, TPB, 0, stream>>>(X, out4, nf4);
}